// Round 3
// baseline (312.701 us; speedup 1.0000x reference)
//
#include <hip/hip_runtime.h>
#include <hip/hip_bf16.h>
#include <hip/hip_fp16.h>
#include <math.h>
#include <string.h>

// Problem constants (from reference)
#define BINSIZE 200
#define BINW 500          // WIDTH / BINSIZE
#define NCLUST 20
#define NREG_OI 200
#define LOG_BINSIZE   5.2983173665480363f   // log(200)
#define LOG_BINWIDTH  6.2146080984221914f   // log(500)
#define LOG_OUTWIDTH 11.5079131920500050f   // log(100000 - 500)

// MEASUREMENT ROUND: frag_kernel is launched TWICE (idempotent write).
// dur_us_delta vs round 1 (285.9) == one L2-warm frag_kernel duration.
// This disambiguates "harness-floor-dominated" vs "gather-bound frag at
// ~110us hiding below the top-5 cutoff (116.4us)".

typedef int   vint2   __attribute__((ext_vector_type(2)));
typedef int   vint4   __attribute__((ext_vector_type(4)));
typedef float vfloat4 __attribute__((ext_vector_type(4)));

// ---------------------------------------------------------------------------
// Phase 1: heights[r, c, b] = log_softmax_b(baseline[g,b] + delta[g,c,b]) - log(200)
// Stored as f16: 200*20*500*2 = 4 MB -> fits per-XCD L2.
// ---------------------------------------------------------------------------
__global__ void heights_kernel(const float* __restrict__ baseline,   // [5000, 500]
                               const float* __restrict__ delta,      // [5000, 20, 500]
                               const int*   __restrict__ regions_oi, // [200]
                               _Float16*    __restrict__ heights)    // [200, 20, 500] (ws)
{
    const int wave = blockIdx.x * 4 + (threadIdx.x >> 6);
    const int lane = threadIdx.x & 63;
    if (wave >= NREG_OI * NCLUST) return;

    const int r = wave / NCLUST;
    const int c = wave % NCLUST;
    const int g = regions_oi[r];

    const float* bptr = baseline + (size_t)g * BINW;
    const float* dptr = delta + ((size_t)g * NCLUST + c) * BINW;

    float u[8];
    float m = -INFINITY;
#pragma unroll
    for (int k = 0; k < 8; ++k) {
        const int b = lane + 64 * k;
        u[k] = (b < BINW)
             ? (bptr[b] + __builtin_nontemporal_load(dptr + b))
             : -INFINITY;
        m = fmaxf(m, u[k]);
    }
#pragma unroll
    for (int off = 32; off > 0; off >>= 1)
        m = fmaxf(m, __shfl_xor(m, off));

    float s = 0.f;
#pragma unroll
    for (int k = 0; k < 8; ++k) {
        const int b = lane + 64 * k;
        if (b < BINW) s += __expf(u[k] - m);
    }
#pragma unroll
    for (int off = 32; off > 0; off >>= 1)
        s += __shfl_xor(s, off);

    const float lse = m + __logf(s);
    _Float16* hptr = heights + (size_t)wave * BINW;
#pragma unroll
    for (int k = 0; k < 8; ++k) {
        const int b = lane + 64 * k;
        if (b < BINW) hptr[b] = (_Float16)(u[k] - lse - LOG_BINSIZE);
    }
}

// ---------------------------------------------------------------------------
// Phase 2: FOUR fragments per thread. UNCHANGED from round 1 — must stay
// byte-identical so the double-launch delta measures exactly this kernel.
// ---------------------------------------------------------------------------
__global__ __launch_bounds__(256)
void frag_kernel(const _Float16* __restrict__ heights, // [200, 20, 500]
                 const int*      __restrict__ coords,  // [N, 2]
                 const int*      __restrict__ lrix,    // [N]
                 const int*      __restrict__ lcix,    // [N]
                 const int*      __restrict__ labels,  // [100000]
                 const float*    __restrict__ inside,  // [1]
                 float*          __restrict__ out,     // [N, 2]
                 int N)                                // 2,000,000
{
    const int q  = blockIdx.x * blockDim.x + threadIdx.x;
    const int f0 = q * 4;
    if (f0 >= N) return;

    const float x  = inside[0];
    const float sg = 1.f / (1.f + __expf(-x));
    const float lp_in  = __logf(sg)       - LOG_BINWIDTH;
    const float lp_out = __logf(1.f - sg) - LOG_OUTWIDTH;

    if (f0 + 3 < N) {
        const vint4 c01 = __builtin_nontemporal_load((const vint4*)coords + 2 * q);
        const vint4 c23 = __builtin_nontemporal_load((const vint4*)coords + 2 * q + 1);
        const vint4 rr  = __builtin_nontemporal_load((const vint4*)lrix + q);
        const vint4 ce  = __builtin_nontemporal_load((const vint4*)lcix + q);

        const int lab0 = labels[ce.x];
        const int lab1 = labels[ce.y];
        const int lab2 = labels[ce.z];
        const int lab3 = labels[ce.w];

        const unsigned bl0 = (unsigned)c01.x / (unsigned)BINSIZE;
        const unsigned br0 = (unsigned)c01.y / (unsigned)BINSIZE;
        const unsigned bl1 = (unsigned)c01.z / (unsigned)BINSIZE;
        const unsigned br1 = (unsigned)c01.w / (unsigned)BINSIZE;
        const unsigned bl2 = (unsigned)c23.x / (unsigned)BINSIZE;
        const unsigned br2 = (unsigned)c23.y / (unsigned)BINSIZE;
        const unsigned bl3 = (unsigned)c23.z / (unsigned)BINSIZE;
        const unsigned br3 = (unsigned)c23.w / (unsigned)BINSIZE;

        const float h0 = (float)heights[((size_t)rr.x * NCLUST + lab0) * BINW + bl0];
        const float h1 = (float)heights[((size_t)rr.y * NCLUST + lab1) * BINW + bl1];
        const float h2 = (float)heights[((size_t)rr.z * NCLUST + lab2) * BINW + bl2];
        const float h3 = (float)heights[((size_t)rr.w * NCLUST + lab3) * BINW + bl3];

        vfloat4 o01, o23;
        o01.x = h0;
        o01.y = (bl0 == br0) ? lp_in : lp_out;
        o01.z = h1;
        o01.w = (bl1 == br1) ? lp_in : lp_out;
        o23.x = h2;
        o23.y = (bl2 == br2) ? lp_in : lp_out;
        o23.z = h3;
        o23.w = (bl3 == br3) ? lp_in : lp_out;
        __builtin_nontemporal_store(o01, (vfloat4*)out + 2 * q);
        __builtin_nontemporal_store(o23, (vfloat4*)out + 2 * q + 1);
    } else {
        for (int f = f0; f < N; ++f) {
            const unsigned bl = (unsigned)coords[2 * f]     / (unsigned)BINSIZE;
            const unsigned br = (unsigned)coords[2 * f + 1] / (unsigned)BINSIZE;
            const int lab = labels[lcix[f]];
            const float h = (float)heights[((size_t)lrix[f] * NCLUST + lab) * BINW + bl];
            out[2 * f]     = h;
            out[2 * f + 1] = (bl == br) ? lp_in : lp_out;
        }
    }
}

// ---------------------------------------------------------------------------
extern "C" void kernel_launch(void* const* d_in, const int* in_sizes, int n_in,
                              void* d_out, int out_size, void* d_ws, size_t ws_size,
                              hipStream_t stream) {
    const float* baseline   = (const float*)d_in[0];
    const float* delta      = (const float*)d_in[1];
    const float* inside     = (const float*)d_in[2];
    const int*   regions_oi = (const int*)d_in[3];
    const int*   coords     = (const int*)d_in[4];
    const int*   lrix       = (const int*)d_in[5];
    const int*   lcix       = (const int*)d_in[6];
    const int*   labels     = (const int*)d_in[7];
    float*       out        = (float*)d_out;
    _Float16*    heights    = (_Float16*)d_ws;   // 200*20*500*2 = 4 MB

    const int N     = in_sizes[4] / 2;           // 2,000,000 fragments
    const int Nquad = (N + 3) / 4;

    heights_kernel<<<(NREG_OI * NCLUST + 3) / 4, 256, 0, stream>>>(
        baseline, delta, regions_oi, heights);

    // Launch 1: the real computation.
    frag_kernel<<<(Nquad + 255) / 256, 256, 0, stream>>>(
        heights, coords, lrix, lcix, labels, inside, out, N);

    // Launch 2: IDENTICAL, idempotent. Exists solely so that
    // dur_us - 285.9 == one (L2-warm) frag_kernel duration.
    // Remove next round once the split of the 286us window is known.
    frag_kernel<<<(Nquad + 255) / 256, 256, 0, stream>>>(
        heights, coords, lrix, lcix, labels, inside, out, N);
}

// Round 5
// 283.040 us; speedup vs baseline: 1.1048x; 1.1048x over previous
//
#include <hip/hip_runtime.h>
#include <hip/hip_bf16.h>
#include <hip/hip_fp16.h>
#include <math.h>
#include <string.h>

// Problem constants (from reference)
#define BINSIZE 200
#define BINW 500          // WIDTH / BINSIZE
#define NCLUST 20
#define NREG_OI 200
#define LOG_BINSIZE   5.2983173665480363f   // log(200)
#define LOG_BINWIDTH  6.2146080984221914f   // log(500)
#define LOG_OUTWIDTH 11.5079131920500050f   // log(100000 - 500)

// Session measurements:
//   frag_kernel (L2-warm)  ~= 26.8 us   (round-3 double-launch experiment)
//   heights_kernel         ~= 5-10 us   (inferred)
//   harness poison/restore ~= 250 us of the 286 us window (untouchable).
// Round-4 failure post-mortem: in_sizes[] are ELEMENT counts, not bytes.
// ncells = in_sizes[7]/4 left 3/4 of labels8 poisoned -> absmax 18.2.
// Fixed: ncells = in_sizes[7]. All other round-4 changes retained.

typedef int   vint2   __attribute__((ext_vector_type(2)));
typedef int   vint4   __attribute__((ext_vector_type(4)));
typedef float vfloat4 __attribute__((ext_vector_type(4)));

#define HBLOCKS 1000   // 4000 (r,c) waves / 4 waves per block
#define LBLOCKS 98     // ceil(100000 cells / 4 per thread / 256)

// ---------------------------------------------------------------------------
// Phase 1 (fused): blocks [0, HBLOCKS) compute the heights table;
// blocks [HBLOCKS, HBLOCKS+LBLOCKS) convert labels i32 -> u8 (values 0..19).
// heights[r, c, b] = log_softmax_b(baseline[g,b] + delta[g,c,b]) - log(200)
// Stored f16: 200*20*500*2 = 4,000,000 B -> per-XCD-L2 resident for phase 2.
// ---------------------------------------------------------------------------
__global__ void heights_kernel(const float* __restrict__ baseline,   // [5000, 500]
                               const float* __restrict__ delta,      // [5000, 20, 500]
                               const int*   __restrict__ regions_oi, // [200]
                               const int*   __restrict__ labels,     // [100000]
                               _Float16*    __restrict__ heights,    // ws +0    (4 MB)
                               unsigned char* __restrict__ labels8,  // ws +4MiB (100 KB)
                               int ncells)
{
    if (blockIdx.x >= HBLOCKS) {
        // ---- labels i32 -> u8 conversion (one vint4 -> packed u8x4 per thread)
        const int t = (blockIdx.x - HBLOCKS) * 256 + threadIdx.x;
        const int i0 = t * 4;
        if (i0 + 3 < ncells) {
            const vint4 l = __builtin_nontemporal_load((const vint4*)labels + t);
            unsigned packed = (unsigned)(l.x & 0xff)
                            | ((unsigned)(l.y & 0xff) << 8)
                            | ((unsigned)(l.z & 0xff) << 16)
                            | ((unsigned)(l.w & 0xff) << 24);
            *(unsigned*)(labels8 + i0) = packed;
        } else {
            for (int i = i0; i < ncells; ++i) labels8[i] = (unsigned char)labels[i];
        }
        return;
    }

    const int wave = blockIdx.x * 4 + (threadIdx.x >> 6);
    const int lane = threadIdx.x & 63;
    if (wave >= NREG_OI * NCLUST) return;

    const int r = wave / NCLUST;
    const int c = wave % NCLUST;
    const int g = regions_oi[r];

    const float* bptr = baseline + (size_t)g * BINW;
    const float* dptr = delta + ((size_t)g * NCLUST + c) * BINW;

    float u[8];
    float m = -INFINITY;
#pragma unroll
    for (int k = 0; k < 8; ++k) {
        const int b = lane + 64 * k;
        // delta rows are read exactly once across the whole grid -> non-temporal
        u[k] = (b < BINW)
             ? (bptr[b] + __builtin_nontemporal_load(dptr + b))
             : -INFINITY;
        m = fmaxf(m, u[k]);
    }
#pragma unroll
    for (int off = 32; off > 0; off >>= 1)
        m = fmaxf(m, __shfl_xor(m, off));

    float s = 0.f;
#pragma unroll
    for (int k = 0; k < 8; ++k) {
        const int b = lane + 64 * k;
        if (b < BINW) s += __expf(u[k] - m);
    }
#pragma unroll
    for (int off = 32; off > 0; off >>= 1)
        s += __shfl_xor(s, off);

    const float lse = m + __logf(s);
    _Float16* hptr = heights + (size_t)wave * BINW;
#pragma unroll
    for (int k = 0; k < 8; ++k) {
        const int b = lane + 64 * k;
        if (b < BINW) hptr[b] = (_Float16)(u[k] - lse - LOG_BINSIZE);
    }
}

// ---------------------------------------------------------------------------
// Phase 2: EIGHT fragments per thread — 4x dwordx4 coords, 2x dwordx4 lrix,
// 2x dwordx4 lcix, 8 u8 label gathers (100 KB table), 8 f16 height gathers
// (4 MB table), 4x dwordx4 stores. Eight independent 2-deep gather chains
// per thread hide L2 latency; streamed arrays are non-temporal.
// ---------------------------------------------------------------------------
__global__ __launch_bounds__(256)
void frag_kernel(const _Float16* __restrict__ heights,      // ws +0
                 const unsigned char* __restrict__ labels8, // ws +4MiB
                 const int*      __restrict__ coords,  // [N, 2]
                 const int*      __restrict__ lrix,    // [N]
                 const int*      __restrict__ lcix,    // [N]
                 const float*    __restrict__ inside,  // [1]
                 float*          __restrict__ out,     // [N, 2]
                 int N)                                // 2,000,000
{
    const int q  = blockIdx.x * blockDim.x + threadIdx.x;
    const int f0 = q * 8;
    if (f0 >= N) return;

    const float x  = inside[0];
    const float sg = 1.f / (1.f + __expf(-x));
    const float lp_in  = __logf(sg)       - LOG_BINWIDTH;
    const float lp_out = __logf(1.f - sg) - LOG_OUTWIDTH;

    if (f0 + 7 < N) {
        // 8 fragments: 64 B coords, 32 B region idx, 32 B cell idx
        vint4 cc[4];
#pragma unroll
        for (int j = 0; j < 4; ++j)
            cc[j] = __builtin_nontemporal_load((const vint4*)coords + 4 * q + j);
        const vint4 r0 = __builtin_nontemporal_load((const vint4*)lrix + 2 * q);
        const vint4 r1 = __builtin_nontemporal_load((const vint4*)lrix + 2 * q + 1);
        const vint4 e0 = __builtin_nontemporal_load((const vint4*)lcix + 2 * q);
        const vint4 e1 = __builtin_nontemporal_load((const vint4*)lcix + 2 * q + 1);

        const int rr[8] = { r0.x, r0.y, r0.z, r0.w, r1.x, r1.y, r1.z, r1.w };
        const int ce[8] = { e0.x, e0.y, e0.z, e0.w, e1.x, e1.y, e1.z, e1.w };

        // first gather round: 8 independent u8 label lookups (100 KB table)
        int lab[8];
#pragma unroll
        for (int k = 0; k < 8; ++k) lab[k] = (int)labels8[ce[k]];

        unsigned bl[8], br[8];
#pragma unroll
        for (int j = 0; j < 4; ++j) {
            bl[2 * j]     = (unsigned)cc[j].x / (unsigned)BINSIZE;
            br[2 * j]     = (unsigned)cc[j].y / (unsigned)BINSIZE;
            bl[2 * j + 1] = (unsigned)cc[j].z / (unsigned)BINSIZE;
            br[2 * j + 1] = (unsigned)cc[j].w / (unsigned)BINSIZE;
        }

        // second gather round: 8 independent f16 height lookups (4 MB table).
        // Index fits int32 (max 200*20*500 - 1 = 1,999,999).
        float h[8];
#pragma unroll
        for (int k = 0; k < 8; ++k) {
            const int idx = (rr[k] * NCLUST + lab[k]) * BINW + (int)bl[k];
            h[k] = (float)heights[idx];
        }

#pragma unroll
        for (int j = 0; j < 4; ++j) {
            vfloat4 o;
            o.x = h[2 * j];
            o.y = (bl[2 * j]     == br[2 * j])     ? lp_in : lp_out;
            o.z = h[2 * j + 1];
            o.w = (bl[2 * j + 1] == br[2 * j + 1]) ? lp_in : lp_out;
            __builtin_nontemporal_store(o, (vfloat4*)out + 4 * q + j);
        }
    } else {
        // scalar tail (not taken for N = 2,000,000; kept for robustness)
        for (int f = f0; f < N; ++f) {
            const unsigned bl = (unsigned)coords[2 * f]     / (unsigned)BINSIZE;
            const unsigned br = (unsigned)coords[2 * f + 1] / (unsigned)BINSIZE;
            const int lab = (int)labels8[lcix[f]];
            const float h = (float)heights[(lrix[f] * NCLUST + lab) * BINW + (int)bl];
            out[2 * f]     = h;
            out[2 * f + 1] = (bl == br) ? lp_in : lp_out;
        }
    }
}

// ---------------------------------------------------------------------------
extern "C" void kernel_launch(void* const* d_in, const int* in_sizes, int n_in,
                              void* d_out, int out_size, void* d_ws, size_t ws_size,
                              hipStream_t stream) {
    const float* baseline   = (const float*)d_in[0];
    const float* delta      = (const float*)d_in[1];
    const float* inside     = (const float*)d_in[2];
    const int*   regions_oi = (const int*)d_in[3];
    const int*   coords     = (const int*)d_in[4];
    const int*   lrix       = (const int*)d_in[5];
    const int*   lcix       = (const int*)d_in[6];
    const int*   labels     = (const int*)d_in[7];
    float*       out        = (float*)d_out;

    _Float16*      heights = (_Float16*)d_ws;                       // +0: 4 MB
    unsigned char* labels8 = (unsigned char*)d_ws + (4u << 20);     // +4MiB: 100 KB

    // in_sizes are ELEMENT counts (verified: in_sizes[4]/2 == 2,000,000 == N).
    const int N      = in_sizes[4] / 2;   // 2,000,000 fragments
    const int ncells = in_sizes[7];       // 100,000 cells
    const int Noct   = (N + 7) / 8;       // 250,000 threads

    heights_kernel<<<HBLOCKS + LBLOCKS, 256, 0, stream>>>(
        baseline, delta, regions_oi, labels, heights, labels8, ncells);

    frag_kernel<<<(Noct + 255) / 256, 256, 0, stream>>>(
        heights, labels8, coords, lrix, lcix, inside, out, N);
}

// Round 6
// 281.695 us; speedup vs baseline: 1.1101x; 1.0048x over previous
//
#include <hip/hip_runtime.h>
#include <hip/hip_bf16.h>
#include <hip/hip_fp16.h>
#include <math.h>
#include <string.h>

// Problem constants (from reference)
#define BINSIZE 200
#define BINW 500          // WIDTH / BINSIZE
#define NCLUST 20
#define NREG_OI 200
#define LOG_BINSIZE   5.2983173665480363f   // log(200)
#define LOG_BINWIDTH  6.2146080984221914f   // log(500)
#define LOG_OUTWIDTH 11.5079131920500050f   // log(100000 - 500)

// Session measurements:
//   round-3 double-launch: frag_kernel(L2-warm) ~= 26.8 us (4-frag, i32 labels)
//   round-5: 8-frag + u8 labels -> dur 283.0 (-2.85); frag ~= 24 us
//   harness poison/restore ~= 250 us of the window (800 MB fill @ ~118 us; untouchable)
// Occupancy ledger: 8-frag = 3906 waves = 15/CU (half); 2-frag = full.
// This round: 4-frag + u8 labels = 7812 waves = 30.5/CU (full) x 4 chains/thread
// -- the untested cell of the {ILP x occupancy} grid.

typedef int   vint2   __attribute__((ext_vector_type(2)));
typedef int   vint4   __attribute__((ext_vector_type(4)));
typedef float vfloat4 __attribute__((ext_vector_type(4)));

#define HBLOCKS 1000   // 4000 (r,c) waves / 4 waves per block
#define LBLOCKS 98     // ceil(100000 cells / 4 per thread / 256)

// ---------------------------------------------------------------------------
// Phase 1 (fused): blocks [0, HBLOCKS) compute the heights table;
// blocks [HBLOCKS, HBLOCKS+LBLOCKS) convert labels i32 -> u8 (values 0..19).
// heights[r, c, b] = log_softmax_b(baseline[g,b] + delta[g,c,b]) - log(200)
// Stored f16: 200*20*500*2 = 4,000,000 B -> per-XCD-L2 resident for phase 2.
// ---------------------------------------------------------------------------
__global__ void heights_kernel(const float* __restrict__ baseline,   // [5000, 500]
                               const float* __restrict__ delta,      // [5000, 20, 500]
                               const int*   __restrict__ regions_oi, // [200]
                               const int*   __restrict__ labels,     // [100000]
                               _Float16*    __restrict__ heights,    // ws +0    (4 MB)
                               unsigned char* __restrict__ labels8,  // ws +4MiB (100 KB)
                               int ncells)
{
    if (blockIdx.x >= HBLOCKS) {
        // ---- labels i32 -> u8 conversion (one vint4 -> packed u8x4 per thread)
        const int t = (blockIdx.x - HBLOCKS) * 256 + threadIdx.x;
        const int i0 = t * 4;
        if (i0 + 3 < ncells) {
            const vint4 l = __builtin_nontemporal_load((const vint4*)labels + t);
            unsigned packed = (unsigned)(l.x & 0xff)
                            | ((unsigned)(l.y & 0xff) << 8)
                            | ((unsigned)(l.z & 0xff) << 16)
                            | ((unsigned)(l.w & 0xff) << 24);
            *(unsigned*)(labels8 + i0) = packed;
        } else {
            for (int i = i0; i < ncells; ++i) labels8[i] = (unsigned char)labels[i];
        }
        return;
    }

    const int wave = blockIdx.x * 4 + (threadIdx.x >> 6);
    const int lane = threadIdx.x & 63;
    if (wave >= NREG_OI * NCLUST) return;

    const int r = wave / NCLUST;
    const int c = wave % NCLUST;
    const int g = regions_oi[r];

    const float* bptr = baseline + (size_t)g * BINW;
    const float* dptr = delta + ((size_t)g * NCLUST + c) * BINW;

    float u[8];
    float m = -INFINITY;
#pragma unroll
    for (int k = 0; k < 8; ++k) {
        const int b = lane + 64 * k;
        // delta rows are read exactly once across the whole grid -> non-temporal
        u[k] = (b < BINW)
             ? (bptr[b] + __builtin_nontemporal_load(dptr + b))
             : -INFINITY;
        m = fmaxf(m, u[k]);
    }
#pragma unroll
    for (int off = 32; off > 0; off >>= 1)
        m = fmaxf(m, __shfl_xor(m, off));

    float s = 0.f;
#pragma unroll
    for (int k = 0; k < 8; ++k) {
        const int b = lane + 64 * k;
        if (b < BINW) s += __expf(u[k] - m);
    }
#pragma unroll
    for (int off = 32; off > 0; off >>= 1)
        s += __shfl_xor(s, off);

    const float lse = m + __logf(s);
    _Float16* hptr = heights + (size_t)wave * BINW;
#pragma unroll
    for (int k = 0; k < 8; ++k) {
        const int b = lane + 64 * k;
        if (b < BINW) hptr[b] = (_Float16)(u[k] - lse - LOG_BINSIZE);
    }
}

// ---------------------------------------------------------------------------
// Phase 2: FOUR fragments per thread — 2x dwordx4 coords, dwordx4 lrix,
// dwordx4 lcix, 4 u8 label gathers (100 KB table), 4 f16 height gathers
// (4 MB table), 2x dwordx4 stores. Full occupancy (7812 waves = 30.5/CU)
// with 4 independent 2-deep gather chains per thread.
// ---------------------------------------------------------------------------
__global__ __launch_bounds__(256)
void frag_kernel(const _Float16* __restrict__ heights,      // ws +0
                 const unsigned char* __restrict__ labels8, // ws +4MiB
                 const int*      __restrict__ coords,  // [N, 2]
                 const int*      __restrict__ lrix,    // [N]
                 const int*      __restrict__ lcix,    // [N]
                 const float*    __restrict__ inside,  // [1]
                 float*          __restrict__ out,     // [N, 2]
                 int N)                                // 2,000,000
{
    const int q  = blockIdx.x * blockDim.x + threadIdx.x;
    const int f0 = q * 4;
    if (f0 >= N) return;

    const float x  = inside[0];
    const float sg = 1.f / (1.f + __expf(-x));
    const float lp_in  = __logf(sg)       - LOG_BINWIDTH;
    const float lp_out = __logf(1.f - sg) - LOG_OUTWIDTH;

    if (f0 + 3 < N) {
        // 4 fragments: 32 B coords, 16 B region idx, 16 B cell idx
        const vint4 c01 = __builtin_nontemporal_load((const vint4*)coords + 2 * q);
        const vint4 c23 = __builtin_nontemporal_load((const vint4*)coords + 2 * q + 1);
        const vint4 rr  = __builtin_nontemporal_load((const vint4*)lrix + q);
        const vint4 ce  = __builtin_nontemporal_load((const vint4*)lcix + q);

        // first gather round: 4 independent u8 label lookups (100 KB table)
        const int lab0 = (int)labels8[ce.x];
        const int lab1 = (int)labels8[ce.y];
        const int lab2 = (int)labels8[ce.z];
        const int lab3 = (int)labels8[ce.w];

        const unsigned bl0 = (unsigned)c01.x / (unsigned)BINSIZE;
        const unsigned br0 = (unsigned)c01.y / (unsigned)BINSIZE;
        const unsigned bl1 = (unsigned)c01.z / (unsigned)BINSIZE;
        const unsigned br1 = (unsigned)c01.w / (unsigned)BINSIZE;
        const unsigned bl2 = (unsigned)c23.x / (unsigned)BINSIZE;
        const unsigned br2 = (unsigned)c23.y / (unsigned)BINSIZE;
        const unsigned bl3 = (unsigned)c23.z / (unsigned)BINSIZE;
        const unsigned br3 = (unsigned)c23.w / (unsigned)BINSIZE;

        // second gather round: 4 independent f16 height lookups (4 MB table).
        // Index fits int32 (max 200*20*500 - 1 = 1,999,999).
        const float h0 = (float)heights[(rr.x * NCLUST + lab0) * BINW + (int)bl0];
        const float h1 = (float)heights[(rr.y * NCLUST + lab1) * BINW + (int)bl1];
        const float h2 = (float)heights[(rr.z * NCLUST + lab2) * BINW + (int)bl2];
        const float h3 = (float)heights[(rr.w * NCLUST + lab3) * BINW + (int)bl3];

        vfloat4 o01, o23;
        o01.x = h0;
        o01.y = (bl0 == br0) ? lp_in : lp_out;
        o01.z = h1;
        o01.w = (bl1 == br1) ? lp_in : lp_out;
        o23.x = h2;
        o23.y = (bl2 == br2) ? lp_in : lp_out;
        o23.z = h3;
        o23.w = (bl3 == br3) ? lp_in : lp_out;
        __builtin_nontemporal_store(o01, (vfloat4*)out + 2 * q);
        __builtin_nontemporal_store(o23, (vfloat4*)out + 2 * q + 1);
    } else {
        // scalar tail (not taken for N = 2,000,000; kept for robustness)
        for (int f = f0; f < N; ++f) {
            const unsigned bl = (unsigned)coords[2 * f]     / (unsigned)BINSIZE;
            const unsigned br = (unsigned)coords[2 * f + 1] / (unsigned)BINSIZE;
            const int lab = (int)labels8[lcix[f]];
            const float h = (float)heights[(lrix[f] * NCLUST + lab) * BINW + (int)bl];
            out[2 * f]     = h;
            out[2 * f + 1] = (bl == br) ? lp_in : lp_out;
        }
    }
}

// ---------------------------------------------------------------------------
extern "C" void kernel_launch(void* const* d_in, const int* in_sizes, int n_in,
                              void* d_out, int out_size, void* d_ws, size_t ws_size,
                              hipStream_t stream) {
    const float* baseline   = (const float*)d_in[0];
    const float* delta      = (const float*)d_in[1];
    const float* inside     = (const float*)d_in[2];
    const int*   regions_oi = (const int*)d_in[3];
    const int*   coords     = (const int*)d_in[4];
    const int*   lrix       = (const int*)d_in[5];
    const int*   lcix       = (const int*)d_in[6];
    const int*   labels     = (const int*)d_in[7];
    float*       out        = (float*)d_out;

    _Float16*      heights = (_Float16*)d_ws;                       // +0: 4 MB
    unsigned char* labels8 = (unsigned char*)d_ws + (4u << 20);     // +4MiB: 100 KB

    // in_sizes are ELEMENT counts (verified: in_sizes[4]/2 == 2,000,000 == N).
    const int N      = in_sizes[4] / 2;   // 2,000,000 fragments
    const int ncells = in_sizes[7];       // 100,000 cells
    const int Nquad  = (N + 3) / 4;       // 500,000 threads

    heights_kernel<<<HBLOCKS + LBLOCKS, 256, 0, stream>>>(
        baseline, delta, regions_oi, labels, heights, labels8, ncells);

    frag_kernel<<<(Nquad + 255) / 256, 256, 0, stream>>>(
        heights, labels8, coords, lrix, lcix, inside, out, N);
}